// Round 19
// baseline (137.257 us; speedup 1.0000x reference)
//
#include <hip/hip_runtime.h>
#include <cfloat>

#define NPTS   16384
#define MATOMS 8192
#define CH     16
#define ADIM   6
#define KNN    16
#define GRPS   4               // 64-lane groups per 256-thread block
#define PTSPG  2               // points per group
#define BIGF   1e10f
#define SLOTS  12              // per-lane per-point capacity (lambda~1.3, P(>12)~1e-8)
#define CHUNK  512
#define NCHUNK (MATOMS/CHUNK)  // 16
#define VMINC  4               // vmin subset = first 2048 atoms (validated stat)
#define NPASS  (VMINC + NCHUNK) // 20

// workspace layout
#define OFF_POS4  0u
#define OFF_TBUF  131072u
#define OFF_ABAT  655360u
#define OFF_GSEG  688128u
#define GSEG_BYTES ((size_t)NPTS * SLOTS * 64 * 2)   // ~25.2 MB
#define WS_NEED_G (OFF_GSEG + GSEG_BYTES)

__device__ __forceinline__ float leakyf(float x) { return x >= 0.0f ? x : 0.2f * x; }

// ---------------------------------------------------------------------------
// Kernel A: per-atom feature MLP t = L3(L2(L1(atomtypes))) + packed pos4
// ---------------------------------------------------------------------------
__global__ void __launch_bounds__(256) prep_kernel(
    const float* __restrict__ atom_xyz,
    const float* __restrict__ atomtypes,
    const int*   __restrict__ atom_batch,
    const float* __restrict__ Wt1, const float* __restrict__ bt1,
    const float* __restrict__ Wt2, const float* __restrict__ bt2,
    const float* __restrict__ Wt3, const float* __restrict__ bt3,
    float4* __restrict__ pos4,
    float*  __restrict__ tbuf,
    int*    __restrict__ abatch)
{
    __shared__ float w1[CH*ADIM], w2[CH*CH], w3[CH*CH], bb1[CH], bb2[CH], bb3[CH];
    const int tid = threadIdx.x;
    if (tid < CH*ADIM) w1[tid] = Wt1[tid];
    if (tid < CH*CH)   { w2[tid] = Wt2[tid]; w3[tid] = Wt3[tid]; }
    if (tid < CH)      { bb1[tid] = bt1[tid]; bb2[tid] = bt2[tid]; bb3[tid] = bt3[tid]; }
    __syncthreads();
    const int m = blockIdx.x * 256 + tid;
    if (m >= MATOMS) return;

    float x[ADIM];
    #pragma unroll
    for (int j = 0; j < ADIM; ++j) x[j] = atomtypes[m*ADIM + j];

    float h0[CH], h1[CH], h2[CH];
    #pragma unroll
    for (int c = 0; c < CH; ++c) {
        float a = 0.0f;
        #pragma unroll
        for (int j = 0; j < ADIM; ++j) a = fmaf(w1[c*ADIM+j], x[j], a);
        h0[c] = leakyf(a + bb1[c]);
    }
    #pragma unroll
    for (int c = 0; c < CH; ++c) {
        float a = 0.0f;
        #pragma unroll
        for (int j = 0; j < CH; ++j) a = fmaf(w2[c*CH+j], h0[j], a);
        h1[c] = leakyf(a + bb2[c]);
    }
    #pragma unroll
    for (int c = 0; c < CH; ++c) {
        float a = 0.0f;
        #pragma unroll
        for (int j = 0; j < CH; ++j) a = fmaf(w3[c*CH+j], h1[j], a);
        h2[c] = leakyf(a + bb3[c]);
    }
    #pragma unroll
    for (int c = 0; c < CH; ++c) tbuf[m*CH + c] = h2[c];

    const float ax = atom_xyz[m*3+0], ay = atom_xyz[m*3+1], az = atom_xyz[m*3+2];
    // np: sum(a*a, -1) = ((ax^2 + ay^2) + az^2), no FMA contraction
    const float a2 = __fadd_rn(__fadd_rn(__fmul_rn(ax,ax), __fmul_rn(ay,ay)), __fmul_rn(az,az));
    pos4[m] = make_float4(ax, ay, az, a2);
    abatch[m] = atom_batch[m];
}

// ---------------------------------------------------------------------------
// Kernel B: 64-lane groups, 2 points each (2048 blocks; LDS ~20 KB on the
// global-seg path -> 8 blocks/CU = up to 32 waves/CU).
//   Scan (64-wide, validated dual-FMA stream, pre-scaled staging, dbuf,
//   issue-after-barrier). Tau: fold partner minima across the 32-boundary
//   then validated 16-pop in 32-lane halves. Tail: per half (pt0 lanes
//   0-31, pt1 lanes 32-63) -> phase C exact select over own+partner columns
//   (lexicographic = order-independent) | r10-validated 32-lane fallback;
//   validated 16-pop lexicographic merge at masks 1..16.
//   Epilogue: lanes {0-15, 32-47}, width-16 shuffles (validated numerics).
// ---------------------------------------------------------------------------
template <int SEG_GLOBAL>
__global__ void __launch_bounds__(256) atom_main_tpl(
    const float* __restrict__ xyz,
    const int*   __restrict__ batch,
    const float4* __restrict__ pos4,
    const float* __restrict__ tbuf,
    const int*   __restrict__ abatch,
    unsigned short* __restrict__ gseg,
    const float* __restrict__ Watt,
    const float* __restrict__ We1, const float* __restrict__ be1,
    const float* __restrict__ We2, const float* __restrict__ be2,
    const float* __restrict__ We3, const float* __restrict__ be3,
    float* __restrict__ out)
{
    __shared__ float lw1t[CH*CH], lw2t[CH*CH], lw3t[CH*CH];
    __shared__ float lb1[CH], lb2[CH], lb3[CH], lwatt[KNN];
    __shared__ unsigned short lbuf[SEG_GLOBAL ? 1 : GRPS*PTSPG*SLOTS*64];
    __shared__ float4 lpos[2][CHUNK];
    const int tid = threadIdx.x;
    lw1t[tid] = We1[(tid & 15)*CH + (tid >> 4)];
    lw2t[tid] = We2[(tid & 15)*CH + (tid >> 4)];
    lw3t[tid] = We3[(tid & 15)*CH + (tid >> 4)];
    if (tid < CH) { lb1[tid] = be1[tid]; lb2[tid] = be2[tid]; lb3[tid] = be3[tid]; lwatt[tid] = Watt[tid]; }

    const int c64 = tid & 63;
    const int grp = tid >> 6;                    // 0..3
    const int n0  = (blockIdx.x * GRPS + grp) * PTSPG;
    const int n1  = n0 + 1;

    const float px0 = xyz[n0*3+0], py0 = xyz[n0*3+1], pz0 = xyz[n0*3+2];
    const float px1 = xyz[n1*3+0], py1 = xyz[n1*3+1], pz1 = xyz[n1*3+2];
    // np: sum(x*x, -1) sequential, no FMA
    const float pn20 = __fadd_rn(__fadd_rn(__fmul_rn(px0,px0), __fmul_rn(py0,py0)), __fmul_rn(pz0,pz0));
    const float pn21 = __fadd_rn(__fadd_rn(__fmul_rn(px1,px1), __fmul_rn(py1,py1)), __fmul_rn(pz1,pz1));
    const int pb0 = batch[n0];
    const int pb1 = batch[n1];

    // prologue: stage chunk 0 into buffer 0 (pre-scaled; -2*x is exact)
    {
        const float4 q0 = pos4[tid];
        const float4 q1 = pos4[tid+256];
        lpos[0][tid]     = make_float4(-2.0f*q0.x, -2.0f*q0.y, -2.0f*q0.z, q0.w);
        lpos[0][tid+256] = make_float4(-2.0f*q1.x, -2.0f*q1.y, -2.0f*q1.z, q1.w);
    }

    float vmin0 = FLT_MAX, vmin1 = FLT_MAX;
    float tauf0 = 0.0f, tauf1 = 0.0f;
    int   skip0 = 0, skip1 = 0;
    int   cnt0 = 0, cnt1 = 0;
    unsigned short* seg0;
    unsigned short* seg1;
    if (SEG_GLOBAL) {
        seg0 = gseg + (size_t)n0 * (SLOTS*64) + c64;
        seg1 = gseg + (size_t)n1 * (SLOTS*64) + c64;
    } else {
        seg0 = &lbuf[(grp*PTSPG + 0) * (SLOTS*64) + c64];
        seg1 = &lbuf[(grp*PTSPG + 1) * (SLOTS*64) + c64];
    }

    for (int g = 0; g < NPASS; ++g) {
        const int cur = g & 1;
        __syncthreads();                     // buf[cur] ready; buf[cur^1] free
        // issue next-chunk loads AFTER the barrier (not drained by it)
        float4 q0, q1;
        const bool pf = (g+1 < NPASS);
        if (pf) {
            const int nc = (g+1 < VMINC) ? (g+1) : (g+1-VMINC);
            const int base = nc*CHUNK;
            q0 = pos4[base+tid]; q1 = pos4[base+tid+256];
        }
        if (g == VMINC) {
            // fold partner minima across 32-boundary (each folded value is a
            // real in-batch atom's lhs), then validated 16-pop per half.
            const float v0f = fminf(vmin0, __shfl_xor(vmin0, 32));
            const float v1f = fminf(vmin1, __shfl_xor(vmin1, 32));
            const int half = c64 >> 5;
            float v = half ? v1f : v0f;
            float tauh = FLT_MAX;
            #pragma unroll
            for (int k = 0; k < KNN; ++k) {
                float d = v;
                d = fminf(d, __shfl_xor(d, 1));
                d = fminf(d, __shfl_xor(d, 2));
                d = fminf(d, __shfl_xor(d, 4));
                d = fminf(d, __shfl_xor(d, 8));
                d = fminf(d, __shfl_xor(d, 16));
                tauh = d;
                if (v == d) v = FLT_MAX;     // remove popped (ties safe)
            }
            const float tauo = __shfl_xor(tauh, 32);
            const float tau0 = half ? tauo : tauh;
            const float tau1 = half ? tauh : tauo;
            skip0 = !(tau0 < BIGF);          // group-uniform
            skip1 = !(tau1 < BIGF);
            tauf0 = skip0 ? -FLT_MAX : tau0 + (1e-5f*(fabsf(pn20) + fabsf(tau0)) + 1e-2f);
            tauf1 = skip1 ? -FLT_MAX : tau1 + (1e-5f*(fabsf(pn21) + fabsf(tau1)) + 1e-2f);
        }
        if (g < VMINC) {
            // dual vmin scan (subset chunks 0..3); lazy global batch check
            #pragma unroll
            for (int t = 0; t < CHUNK/64; ++t) {
                const int il = t*64 + c64;
                const float4 a = lpos[cur][il];
                const float lhs0 = fmaf(pz0, a.z, fmaf(py0, a.y, fmaf(px0, a.x, a.w)));
                const float lhs1 = fmaf(pz1, a.z, fmaf(py1, a.y, fmaf(px1, a.x, a.w)));
                if (lhs0 < vmin0) { if (abatch[g*CHUNK + il] == pb0) vmin0 = lhs0; }
                if (lhs1 < vmin1) { if (abatch[g*CHUNK + il] == pb1) vmin1 = lhs1; }
            }
        } else {
            // dual lean distance-only filter scan (3 FMA + cmp per point)
            const int cb = g - VMINC;
            #pragma unroll
            for (int t = 0; t < CHUNK/64; ++t) {
                const int il = t*64 + c64;
                const float4 a = lpos[cur][il];
                const float lhs0 = fmaf(pz0, a.z, fmaf(py0, a.y, fmaf(px0, a.x, a.w)));
                const float lhs1 = fmaf(pz1, a.z, fmaf(py1, a.y, fmaf(px1, a.x, a.w)));
                const int gi = cb*CHUNK + il;
                if (lhs0 <= tauf0) {
                    if (cnt0 < SLOTS) seg0[cnt0*64] = (unsigned short)gi;
                    ++cnt0;
                }
                if (lhs1 <= tauf1) {
                    if (cnt1 < SLOTS) seg1[cnt1*64] = (unsigned short)gi;
                    ++cnt1;
                }
            }
        }
        if (pf) {                            // write-late: loads landed by now
            lpos[cur^1][tid]     = make_float4(-2.0f*q0.x, -2.0f*q0.y, -2.0f*q0.z, q0.w);
            lpos[cur^1][tid+256] = make_float4(-2.0f*q1.x, -2.0f*q1.y, -2.0f*q1.z, q1.w);
        }
    }

    // ---- per-point overflow guards (64-lane or-reduce, uniform control)
    int ovf0 = skip0 | (cnt0 > SLOTS);
    ovf0 |= __shfl_xor(ovf0, 1);
    ovf0 |= __shfl_xor(ovf0, 2);
    ovf0 |= __shfl_xor(ovf0, 4);
    ovf0 |= __shfl_xor(ovf0, 8);
    ovf0 |= __shfl_xor(ovf0, 16);
    ovf0 |= __shfl_xor(ovf0, 32);
    int ovf1 = skip1 | (cnt1 > SLOTS);
    ovf1 |= __shfl_xor(ovf1, 1);
    ovf1 |= __shfl_xor(ovf1, 2);
    ovf1 |= __shfl_xor(ovf1, 4);
    ovf1 |= __shfl_xor(ovf1, 8);
    ovf1 |= __shfl_xor(ovf1, 16);
    ovf1 |= __shfl_xor(ovf1, 32);
    const int cnt0p = __shfl_xor(cnt0, 32);  // partner-column counts
    const int cnt1p = __shfl_xor(cnt1, 32);

    // ---- tail in 32-lane halves: lanes 0-31 -> point0, lanes 32-63 -> point1
    const int half = c64 >> 5;
    const int hl   = c64 & 31;
    const float mpx = half ? px1 : px0;
    const float mpy = half ? py1 : py0;
    const float mpz = half ? pz1 : pz0;
    const float mpn2 = half ? pn21 : pn20;
    const int   mpb  = half ? pb1 : pb0;
    const int   movf = half ? ovf1 : ovf0;
    const int   mcA  = half ? cnt1  : cnt0;   // own column count
    const int   mcB  = half ? cnt1p : cnt0p;  // partner column count
    const unsigned short* msegA;
    const unsigned short* msegB;
    if (SEG_GLOBAL) {
        const unsigned short* base = gseg + (size_t)(half ? n1 : n0) * (SLOTS*64);
        msegA = base + c64;
        msegB = base + (c64 ^ 32);
    } else {
        const unsigned short* base = &lbuf[(grp*PTSPG + half) * (SLOTS*64)];
        msegA = base + c64;
        msegB = base + (c64 ^ 32);
    }

    float bd[KNN]; int bi[KNN];
    #pragma unroll
    for (int j = 0; j < KNN; ++j) { bd[j] = FLT_MAX; bi[j] = 0x7fffffff; }

    if (movf) {
        // r10-validated 32-lane full insert-scan fallback (per half; rare)
        for (int t = 0; t < MATOMS/32; ++t) {
            const int i = t*32 + hl;
            const float4 a = pos4[i];
            const int ab = abatch[i];
            const float dot = fmaf(mpz, a.z, fmaf(mpy, a.y, __fmul_rn(mpx, a.x)));
            float d2 = __fsub_rn(__fadd_rn(mpn2, a.w), 2.0f * dot);
            d2 = (ab == mpb) ? d2 : BIGF;
            if (d2 < bd[KNN-1]) {
                float d = d2; int id = i;
                #pragma unroll
                for (int j = 0; j < KNN; ++j) {
                    const bool sw = d < bd[j];
                    const float od = bd[j]; const int oi = bi[j];
                    bd[j] = sw ? d  : bd[j];
                    bi[j] = sw ? id : bi[j];
                    d  = sw ? od : d;
                    id = sw ? oi : id;
                }
            }
        }
    } else {
        // Phase C: EXACT d2 + EXACT batch + lexicographic (d, idx) insert
        // (order-independent-exact) over own column then partner column.
        for (int s = 0; s < mcA; ++s) {
            const int i = (int)msegA[s*64];
            const float4 a = pos4[i];
            const float dot = fmaf(mpz, a.z, fmaf(mpy, a.y, __fmul_rn(mpx, a.x)));
            const float d2 = __fsub_rn(__fadd_rn(mpn2, a.w), 2.0f * dot);
            if (abatch[i] == mpb && d2 <= bd[KNN-1]) {
                float d = d2; int id = i;
                #pragma unroll
                for (int j = 0; j < KNN; ++j) {
                    const bool sw = (d < bd[j]) || (d == bd[j] && id < bi[j]);
                    const float od = bd[j]; const int oi = bi[j];
                    bd[j] = sw ? d  : bd[j];
                    bi[j] = sw ? id : bi[j];
                    d  = sw ? od : d;
                    id = sw ? oi : id;
                }
            }
        }
        for (int s = 0; s < mcB; ++s) {
            const int i = (int)msegB[s*64];
            const float4 a = pos4[i];
            const float dot = fmaf(mpz, a.z, fmaf(mpy, a.y, __fmul_rn(mpx, a.x)));
            const float d2 = __fsub_rn(__fadd_rn(mpn2, a.w), 2.0f * dot);
            if (abatch[i] == mpb && d2 <= bd[KNN-1]) {
                float d = d2; int id = i;
                #pragma unroll
                for (int j = 0; j < KNN; ++j) {
                    const bool sw = (d < bd[j]) || (d == bd[j] && id < bi[j]);
                    const float od = bd[j]; const int oi = bi[j];
                    bd[j] = sw ? d  : bd[j];
                    bi[j] = sw ? id : bi[j];
                    d  = sw ? od : d;
                    id = sw ? oi : id;
                }
            }
        }
    }

    // ---- final merge: 16 pops over the 32-lane half, lexicographic (d,idx)
    int idxk[KNN];
    #pragma unroll
    for (int k = 0; k < KNN; ++k) {
        float d = bd[0]; int i = bi[0];
        #pragma unroll
        for (int m = 1; m <= 16; m <<= 1) {
            const float pd = __shfl_xor(d, m);
            const int   pi = __shfl_xor(i, m);
            const bool take = (pd < d) || (pd == d && pi < i);
            d = take ? pd : d;
            i = take ? pi : i;
        }
        idxk[k] = i;
        const bool win = (bd[0] == d) && (bi[0] == i);
        if (win) {
            #pragma unroll
            for (int j = 0; j < KNN-1; ++j) { bd[j] = bd[j+1]; bi[j] = bi[j+1]; }
            bd[KNN-1] = FLT_MAX; bi[KNN-1] = 0x7fffffff;
        }
    }

    // ---- epilogue on lanes {0-15, 32-47}: validated numerics, width-16
    // shuffles confined to each 16-lane sub-half.
    if ((c64 & 16) == 0) {
        const int c = c64 & 15;
        const int myn = half ? n1 : n0;

        float ac0 = 0.0f, ac1 = 0.0f, ac2 = 0.0f;
        #pragma unroll
        for (int k = 0; k < KNN; ++k) {
            const int j = idxk[k];
            const float4 a = pos4[j];
            const float v0 = __fsub_rn(mpx, a.x);
            const float v1 = __fsub_rn(mpy, a.y);
            const float v2 = __fsub_rn(mpz, a.z);
            // np: dists = sum(vecs*vecs, -1), sequential, no FMA (recomputed)
            const float dist = __fadd_rn(__fadd_rn(__fmul_rn(v0,v0), __fmul_rn(v1,v1)), __fmul_rn(v2,v2));
            const float w = 1.0f / __fadd_rn(dist, 1e-8f);   // power(x, -1.0)
            const float nv0 = __fmul_rn(v0, w);
            const float nv1 = __fmul_rn(v1, w);
            const float nv2 = __fmul_rn(v2, w);
            const float fc = tbuf[(size_t)j * CH + c];
            const float fw = __fmul_rn(fc, lwatt[k]);
            ac0 = fmaf(nv0, fw, ac0);
            ac1 = fmaf(nv1, fw, ac1);
            ac2 = fmaf(nv2, fw, ac2);
        }
        const float s = __fadd_rn(__fadd_rn(__fmul_rn(ac0,ac0), __fmul_rn(ac1,ac1)),
                                  __fmul_rn(ac2,ac2));
        const float fx = sqrtf(s);

        float a1 = 0.0f;
        #pragma unroll
        for (int j = 0; j < CH; ++j) {
            const float fj = __shfl(fx, j, 16);
            a1 = fmaf(lw1t[j*CH + c], fj, a1);
        }
        const float g1 = leakyf(a1 + lb1[c]);

        float a2 = 0.0f;
        #pragma unroll
        for (int j = 0; j < CH; ++j) {
            const float gj = __shfl(g1, j, 16);
            a2 = fmaf(lw2t[j*CH + c], gj, a2);
        }
        const float g2 = leakyf(a2 + lb2[c]);

        float a3 = 0.0f;
        #pragma unroll
        for (int j = 0; j < CH; ++j) {
            const float gj = __shfl(g2, j, 16);
            a3 = fmaf(lw3t[j*CH + c], gj, a3);
        }
        out[(size_t)myn*CH + c] = a3 + lb3[c];
    }
}

// ---------------------------------------------------------------------------
extern "C" void kernel_launch(void* const* d_in, const int* in_sizes, int n_in,
                              void* d_out, int out_size, void* d_ws, size_t ws_size,
                              hipStream_t stream)
{
    (void)in_sizes; (void)n_in; (void)out_size;
    const float* xyz        = (const float*)d_in[0];
    const float* atom_xyz   = (const float*)d_in[1];
    const float* atomtypes  = (const float*)d_in[2];
    const int*   batch      = (const int*)d_in[3];
    const int*   atom_batch = (const int*)d_in[4];
    const float* Wt1 = (const float*)d_in[5];
    const float* bt1 = (const float*)d_in[6];
    const float* Wt2 = (const float*)d_in[7];
    const float* bt2 = (const float*)d_in[8];
    const float* Wt3 = (const float*)d_in[9];
    const float* bt3 = (const float*)d_in[10];
    const float* Watt = (const float*)d_in[11];
    const float* We1 = (const float*)d_in[12];
    const float* be1 = (const float*)d_in[13];
    const float* We2 = (const float*)d_in[14];
    const float* be2 = (const float*)d_in[15];
    const float* We3 = (const float*)d_in[16];
    const float* be3 = (const float*)d_in[17];

    char* ws = (char*)d_ws;
    float4* pos4  = (float4*)(ws + OFF_POS4);
    float*  tbuf  = (float*)(ws + OFF_TBUF);
    int*    abat  = (int*)(ws + OFF_ABAT);
    float*  out   = (float*)d_out;

    hipLaunchKernelGGL(prep_kernel, dim3(MATOMS/256), dim3(256), 0, stream,
                       atom_xyz, atomtypes, atom_batch,
                       Wt1, bt1, Wt2, bt2, Wt3, bt3,
                       pos4, tbuf, abat);

    if (ws_size >= WS_NEED_G) {
        unsigned short* gseg = (unsigned short*)(ws + OFF_GSEG);
        hipLaunchKernelGGL((atom_main_tpl<1>), dim3(NPTS/(GRPS*PTSPG)), dim3(256), 0, stream,
                           xyz, batch, pos4, tbuf, abat, gseg,
                           Watt, We1, be1, We2, be2, We3, be3,
                           out);
    } else {
        hipLaunchKernelGGL((atom_main_tpl<0>), dim3(NPTS/(GRPS*PTSPG)), dim3(256), 0, stream,
                           xyz, batch, pos4, tbuf, abat, (unsigned short*)nullptr,
                           Watt, We1, be1, We2, be2, We3, be3,
                           out);
    }
}